// Round 15
// baseline (181.980 us; speedup 1.0000x reference)
//
#include <hip/hip_runtime.h>
#include <hip/hip_bf16.h>
#include <math.h>

#define N_TOK 2048
#define C_DIM 512
#define H_NUM 8
#define DH 64
#define M_LM 64
#define SEG 32
#define KL 4
#define SCALE 0.125f

typedef __attribute__((ext_vector_type(8))) short short8;
typedef __attribute__((ext_vector_type(8))) unsigned short ushort8v;
typedef __attribute__((ext_vector_type(4))) float f32x4;

__device__ inline unsigned short f2bf(float f) {
  unsigned u = __float_as_uint(f);
  u += 0x7FFF + ((u >> 16) & 1);
  return (unsigned short)(u >> 16);
}
__device__ inline float bf2f(unsigned short h) {
  return __uint_as_float(((unsigned)h) << 16);
}

// LDS swizzle for the MFMA GEMM (R7-proven): k-octet stride 1024B is 0 mod 32
// banks; XOR row bits with ko, same on write and read => layout-only.
__device__ inline int swz(int ko, int row) {
  return ((ko * 64 + row) * 8) ^ (ko << 3);
}

// gemm_qk staging rotation (R10-proven: conflicts 3.15M -> 0).
__device__ inline int qrot(int k, int c) {
  return (c & ~3) | ((c + (k >> 3)) & 3);
}

// ---------------------------------------------------------------------------
// Q/K fp32 GEMM — R13 body (64x64, BK=32, rotation, fused bit-exact centroid
// in the K-role epilogue, no fp32 K store). CLOSED at ~92% of its LDS-pipe
// floor (8192 ds_read_b128/CU x 12cyc = 41us; measured 44.5).
// ---------------------------------------------------------------------------
__global__ __launch_bounds__(256) void gemm_qk(
    const float* __restrict__ A, const float* __restrict__ B,
    float* __restrict__ out_q, unsigned short* __restrict__ kbf,
    float* __restrict__ cent)
{
  __shared__ float As[32][68];   // [k][m], pad->16B-aligned rows
  __shared__ float Bs[32][68];   // [k][j]
  int tid = threadIdx.x;
  int tx = tid & 15, ty = tid >> 4;
  int row0 = blockIdx.y << 6;
  int col0 = blockIdx.x << 6;
  float acc[4][4] = {};
  int kk = tid & 31, rr = tid >> 5;   // staging: 32 k-cols x 8 row-groups

  float pa[8], pb[8];
#pragma unroll
  for (int i = 0; i < 8; i++) {
    pa[i] = A[(size_t)(row0 + rr + i * 8) * 512 + kk];
    pb[i] = B[(size_t)(col0 + rr + i * 8) * 512 + kk];
  }

  for (int k0 = 0; k0 < 512; k0 += 32) {
    __syncthreads();
#pragma unroll
    for (int i = 0; i < 8; i++) {
      As[kk][qrot(kk, rr + i * 8)] = pa[i];
      Bs[kk][qrot(kk, rr + i * 8)] = pb[i];
    }
    __syncthreads();
    if (k0 + 32 < 512) {
#pragma unroll
      for (int i = 0; i < 8; i++) {
        pa[i] = A[(size_t)(row0 + rr + i * 8) * 512 + k0 + 32 + kk];
        pb[i] = B[(size_t)(col0 + rr + i * 8) * 512 + k0 + 32 + kk];
      }
    }
#pragma unroll
    for (int kk2 = 0; kk2 < 32; kk2++) {
      const int a2 = kk2 >> 3;
      float ar[4], br[4];
      *(float4*)ar = *(const float4*)&As[kk2][ty << 2];
      *(float4*)br = *(const float4*)&Bs[kk2][tx << 2];
      float a[4], b[4];
#pragma unroll
      for (int j = 0; j < 4; j++) {
        a[j] = ar[(j + a2) & 3];
        b[j] = br[(j + a2) & 3];
      }
#pragma unroll
      for (int i = 0; i < 4; i++)
#pragma unroll
        for (int j = 0; j < 4; j++) acc[i][j] += a[i] * b[j];
    }
  }

  int role = col0 >> 9;
  int h = (col0 >> 6) & 7;
  if (role == 0) {
#pragma unroll
    for (int i = 0; i < 4; i++) {
      int n = row0 + (ty << 2) + i;
#pragma unroll
      for (int j = 0; j < 4; j++) {
        int d = (tx << 2) + j;
        out_q[(size_t)((h << 11) + n) * DH + d] = acc[i][j];
      }
    }
  } else {
    // bf16 K store + exact-order fused centroid (reuses dead As/Bs).
    __syncthreads();   // all lanes done reading As/Bs from the main loop
#pragma unroll
    for (int i = 0; i < 4; i++) {
      int nl = (ty << 2) + i;          // local row 0..63
#pragma unroll
      for (int j = 0; j < 4; j++) {
        int d = (tx << 2) + j;
        float v = acc[i][j];
        kbf[(size_t)((h << 11) + row0 + nl) * DH + d] = f2bf(v);
        if (nl < 32) As[nl][d] = v; else Bs[nl - 32][d] = v;
      }
    }
    __syncthreads();
    if (tid < 128) {
      int m_loc = tid >> 6, d = tid & 63;
      float s = 0.f;
      if (m_loc == 0) {
#pragma unroll
        for (int ss = 0; ss < SEG; ss++) s += As[ss][d];   // ascending n
      } else {
#pragma unroll
        for (int ss = 0; ss < SEG; ss++) s += Bs[ss][d];   // ascending n
      }
      int m = (row0 >> 5) + m_loc;
      cent[(h << 12) + (m << 6) + d] = s * (1.0f / SEG);
    }
  }
}

// ---------------------------------------------------------------------------
// Fused 2-term bf16 splits for x (rows 2048), w_qkv V-rows (512), w_proj (512).
// (R2 version, byte-identical.)
// ---------------------------------------------------------------------------
__global__ void split3_kernel(const float* __restrict__ x, const float* __restrict__ wv,
                              const float* __restrict__ wp,
                              unsigned short* __restrict__ X2,
                              unsigned short* __restrict__ W2v,
                              unsigned short* __restrict__ WP2)
{
  int idx = blockIdx.x * 256 + threadIdx.x;   // 0 .. 1572863
  const float* src; unsigned short* dst; int li;
  if (idx < 1048576)      { src = x;  dst = X2;  li = idx; }
  else if (idx < 1310720) { src = wv; dst = W2v; li = idx - 1048576; }
  else                    { src = wp; dst = WP2; li = idx - 1310720; }
  int r = li >> 9, k = li & 511;
  float a = src[li];
  unsigned short h1 = f2bf(a);
  float r1 = a - bf2f(h1);
  dst[(size_t)(r << 10) + k] = h1;
  dst[(size_t)(r << 10) + 512 + k] = f2bf(r1);
}

// ---------------------------------------------------------------------------
// bf16-split MFMA GEMM, 3 products + LDS XOR swizzle (R7-proven).
// mode 0: V-scatter as SINGLE bf16 -> ov16[(h<<11)+row][d]
// mode 1: ofull = acc + bias (fp32).
// ---------------------------------------------------------------------------
__global__ __launch_bounds__(256) void gemm_mfma(
    const unsigned short* __restrict__ A2, const unsigned short* __restrict__ B2,
    unsigned short* __restrict__ ov16, float* __restrict__ ofull,
    const float* __restrict__ bias, int ldout, int mode)
{
  __shared__ short Al[4096];
  __shared__ short Bl[4096];
  int tid = threadIdx.x;
  int lane = tid & 63, w = tid >> 6;
  int row0 = blockIdx.y << 6, col0 = blockIdx.x << 6;
  int wr = (w >> 1) * 32, wc = (w & 1) * 32;
  int m_lo = tid & 7, h8 = (tid >> 3) & 7, m_hi = tid >> 6;
  int ms = m_hi * 8 + m_lo;  // 0..31
  int q = lane >> 4, ln = lane & 15;

  f32x4 acc[2][2];
#pragma unroll
  for (int mi = 0; mi < 2; mi++)
#pragma unroll
    for (int ni = 0; ni < 2; ni++)
#pragma unroll
      for (int r = 0; r < 4; r++) acc[mi][ni][r] = 0.0f;

  for (int s = 0; s < 24; s++) {
    int ka = (s < 8) ? s * 64 : (s < 16) ? 512 + (s - 8) * 64 : (s - 16) * 64;
    int kb = (s < 8) ? s * 64 : (s < 16) ? (s - 8) * 64 : 512 + (s - 16) * 64;
    short8 a0 = *(const short8*)(A2 + (size_t)(row0 + ms) * 1024 + ka + h8 * 8);
    short8 a1 = *(const short8*)(A2 + (size_t)(row0 + ms + 32) * 1024 + ka + h8 * 8);
    short8 b0 = *(const short8*)(B2 + (size_t)(col0 + ms) * 1024 + kb + h8 * 8);
    short8 b1 = *(const short8*)(B2 + (size_t)(col0 + ms + 32) * 1024 + kb + h8 * 8);
    __syncthreads();
    *(short8*)&Al[swz(h8, ms)] = a0;
    *(short8*)&Al[swz(h8, ms + 32)] = a1;
    *(short8*)&Bl[swz(h8, ms)] = b0;
    *(short8*)&Bl[swz(h8, ms + 32)] = b1;
    __syncthreads();
    short8 af[2][2], bf[2][2];
#pragma unroll
    for (int sub = 0; sub < 2; sub++)
#pragma unroll
      for (int i = 0; i < 2; i++) {
        af[sub][i] = *(const short8*)&Al[swz(sub * 4 + q, wr + i * 16 + ln)];
        bf[sub][i] = *(const short8*)&Bl[swz(sub * 4 + q, wc + i * 16 + ln)];
      }
#pragma unroll
    for (int sub = 0; sub < 2; sub++)
#pragma unroll
      for (int mi = 0; mi < 2; mi++)
#pragma unroll
        for (int ni = 0; ni < 2; ni++)
          acc[mi][ni] = __builtin_amdgcn_mfma_f32_16x16x32_bf16(
              af[sub][mi], bf[sub][ni], acc[mi][ni], 0, 0, 0);
  }

  if (mode == 0) {
    int hh = (col0 >> 6) & 7;
#pragma unroll
    for (int mi = 0; mi < 2; mi++)
#pragma unroll
      for (int ni = 0; ni < 2; ni++)
#pragma unroll
        for (int r = 0; r < 4; r++) {
          int row = row0 + wr + mi * 16 + q * 4 + r;
          int d = wc + ni * 16 + ln;
          ov16[(size_t)((hh << 11) + row) * DH + d] = f2bf(acc[mi][ni][r]);
        }
  } else {
#pragma unroll
    for (int mi = 0; mi < 2; mi++)
#pragma unroll
      for (int ni = 0; ni < 2; ni++)
#pragma unroll
        for (int r = 0; r < 4; r++) {
          int row = row0 + wr + mi * 16 + q * 4 + r;
          int col = col0 + wc + ni * 16 + ln;
          ofull[(size_t)row * ldout + col] = acc[mi][ni][r] + bias[col];
        }
  }
}

// ---------------------------------------------------------------------------
// FUSED route + top-4 + sparse attention (R14 body). This round's single
// change: HEAD-PINNED XCD SWIZZLE. MI355X dispatch round-robins blocks
// across the 8 XCDs by low blockIdx bits; with 8 heads and per-head K/V of
// 512 KB bf16, mapping h = blockIdx&7 pins each head's gather working set
// (+16 KB cent) into ONE XCD's private 4 MB L2 instead of streaming all
// 4 MB of heads through every XCD. Pure block->query reassignment: per-query
// arithmetic, values and output addresses untouched (placement-independent
// correctness), so absmax must stay 0.00048828125.
// ---------------------------------------------------------------------------
__global__ __launch_bounds__(256) void route_attn_kernel(
    const float* __restrict__ qb, const float* __restrict__ cent,
    const unsigned short* __restrict__ kbf, const unsigned short* __restrict__ vbf,
    unsigned short* __restrict__ ao2)
{
  __shared__ float centT[64][65];
  __shared__ float qs[4][64];
  __shared__ float probs[4][132];   // [wave][si*33 + ss]
  int tid = threadIdx.x;
  int wave = tid >> 6, lane = tid & 63;
  int b = blockIdx.x;               // 0..4095
  int h = b & 7;                    // head -> XCD (round-robin on low bits)
  int n4 = (b >> 3) << 2;           // first token row of this block
  int qi = (h << 11) + n4 + wave;
  int n = n4 + wave;

  // ---- route phase (frozen math) ----
  qs[wave][lane] = qb[(size_t)qi * DH + lane];
  const float4* c4 = (const float4*)(cent + ((size_t)h << 12));
#pragma unroll
  for (int i = 0; i < 4; i++) {
    int f4 = tid + 256 * i;       // 0..1023
    int m = f4 >> 4;
    int d0 = (f4 & 15) * 4;
    float4 v = c4[f4];
    centT[d0][m] = v.x; centT[d0 + 1][m] = v.y;
    centT[d0 + 2][m] = v.z; centT[d0 + 3][m] = v.w;
  }
  __syncthreads();
  float dot = 0.f;
#pragma unroll
  for (int d = 0; d < 64; d++) dot += qs[wave][d] * centT[d][lane];
  float val = dot * SCALE;
  int segArr[4];
  for (int r = 0; r < KL; r++) {
    float v = val;
    int id = lane;
#pragma unroll
    for (int off = 32; off; off >>= 1) {
      float ov = __shfl_xor(v, off, 64);
      int oi = __shfl_xor(id, off, 64);
      if (ov > v || (ov == v && oi < id)) { v = ov; id = oi; }
    }
    segArr[r] = id;                  // all lanes converged to the same id
    if (lane == id) val = -INFINITY;
  }

  // ---- attn phase (frozen math; q fragments from qs, same bits) ----
  const float* qrow = &qs[wave][0];
  float4 qreg[4];
#pragma unroll
  for (int j = 0; j < 2; j++) {
    qreg[j * 2]     = *(const float4*)(qrow + ((lane & 3) + 4 * j) * 8);
    qreg[j * 2 + 1] = *(const float4*)(qrow + ((lane & 3) + 4 * j) * 8 + 4);
  }

  float e[8];
  float score[8];
#pragma unroll
  for (int g = 0; g < 8; g++) {
    int seg = segArr[g >> 1];
    int key_n = seg * SEG + (lane >> 2) + 16 * (g & 1);
    const unsigned short* krow = kbf + ((size_t)(h << 11) + key_n) * DH;
    float a0 = 0.f, a1 = 0.f, a2 = 0.f, a3 = 0.f;
#pragma unroll
    for (int j = 0; j < 2; j++) {
      ushort8v kv = *(const ushort8v*)(krow + ((lane & 3) + 4 * j) * 8);
      float4 q0 = qreg[j * 2], q1 = qreg[j * 2 + 1];
      a0 += q0.x * bf2f(kv[0]); a1 += q0.y * bf2f(kv[1]);
      a2 += q0.z * bf2f(kv[2]); a3 += q0.w * bf2f(kv[3]);
      a0 += q1.x * bf2f(kv[4]); a1 += q1.y * bf2f(kv[5]);
      a2 += q1.z * bf2f(kv[6]); a3 += q1.w * bf2f(kv[7]);
    }
    float acc = (a0 + a1) + (a2 + a3);
    acc += __shfl_xor(acc, 1, 64);
    acc += __shfl_xor(acc, 2, 64);
    score[g] = acc * SCALE;
  }
  float mx = score[0];
#pragma unroll
  for (int g = 1; g < 8; g++) mx = fmaxf(mx, score[g]);
#pragma unroll
  for (int off = 4; off < 64; off <<= 1) mx = fmaxf(mx, __shfl_xor(mx, off, 64));
  float ls = 0.f;
#pragma unroll
  for (int g = 0; g < 8; g++) { e[g] = expf(score[g] - mx); ls += e[g]; }
#pragma unroll
  for (int off = 4; off < 64; off <<= 1) ls += __shfl_xor(ls, off, 64);
  float inv = 1.0f / ls;
  if ((lane & 3) == 0) {
#pragma unroll
    for (int g = 0; g < 8; g++)
      probs[wave][(g >> 1) * 33 + (lane >> 2) + 16 * (g & 1)] = e[g] * inv;
  }
  __syncthreads();

  // PV
  int gi = lane >> 4, lx = lane & 15;
  int rh = lx >> 3, dl = lx & 7;
  int seg = segArr[gi];
  const unsigned short* vbase = vbf + ((size_t)(h << 11) + seg * SEG) * DH + dl * 8;
  float o[8] = {};
#pragma unroll
  for (int ss = 0; ss < 16; ss++) {
    int row = rh * 16 + ss;
    float p = probs[wave][gi * 33 + row];
    ushort8v vv = *(const ushort8v*)(vbase + (size_t)row * DH);
#pragma unroll
    for (int j = 0; j < 8; j++) o[j] += p * bf2f(vv[j]);
  }
#pragma unroll
  for (int off = 8; off < 64; off <<= 1) {
#pragma unroll
    for (int j = 0; j < 8; j++) o[j] += __shfl_xor(o[j], off, 64);
  }
  if (lane < 8) {
    ushort8v hi8, lo8;
#pragma unroll
    for (int j = 0; j < 8; j++) {
      unsigned short hb = f2bf(o[j]);
      hi8[j] = (short)hb;
      lo8[j] = (short)f2bf(o[j] - bf2f(hb));
    }
    *(ushort8v*)(ao2 + (size_t)n * 1024 + (h << 6) + (lane << 3)) = hi8;
    *(ushort8v*)(ao2 + (size_t)n * 1024 + 512 + (h << 6) + (lane << 3)) = lo8;
  }
}

// ---------------------------------------------------------------------------
extern "C" void kernel_launch(void* const* d_in, const int* in_sizes, int n_in,
                              void* d_out, int out_size, void* d_ws, size_t ws_size,
                              hipStream_t stream)
{
  const float* x      = (const float*)d_in[0];   // (1,2048,512)
  const float* w_qkv  = (const float*)d_in[1];   // (1536,512)
  const float* w_proj = (const float*)d_in[2];   // (512,512)
  const float* b_proj = (const float*)d_in[3];   // (512,)
  float* out = (float*)d_out;                    // (1,2048,512)

  float* base = (float*)d_ws;
  float* qbuf = base;                                        // 1,048,576 f
  // base+1048576 slot free (fp32 K dead since R13)
  unsigned short* vbf = (unsigned short*)(base + 2097152);   // 8x2048x64 bf16
  unsigned short* kbf = (unsigned short*)(base + 2621440);   // 8x2048x64 bf16
  float* cent = base + 3145728;                              // 32,768 f
  unsigned short* X2  = (unsigned short*)(base + 3244032);   // 2048x1024 bf16 (2-term)
  unsigned short* W2v = (unsigned short*)(base + 4292608);   // 512x1024  (V rows of w_qkv)
  unsigned short* WP2 = (unsigned short*)(base + 4554752);   // 512x1024  (w_proj)
  unsigned short* AO2 = X2;  // overlay: X2 dead after V GEMM

  // 1. fused 2-term bf16 splits (x, V-rows of w_qkv, w_proj)
  split3_kernel<<<6144, 256, 0, stream>>>(x, w_qkv + 1024 * 512, w_proj,
                                          X2, W2v, WP2);
  // 2. Q/K fp32 GEMM (R13 body, chain frozen) + bf16 K + fused exact centroid
  {
    dim3 grid(1024 / 64, N_TOK / 64);
    gemm_qk<<<grid, 256, 0, stream>>>(x, w_qkv, qbuf, kbf, cent);
  }
  // 3. V via bf16-split MFMA (swizzled LDS) -> single-bf16 vbf
  {
    dim3 grid(512 / 64, N_TOK / 64);
    gemm_mfma<<<grid, 256, 0, stream>>>(X2, W2v, vbf, nullptr, nullptr, 0, 0);
  }
  // 4. fused route + top-4 + attn (head-pinned XCD swizzle) -> 2-term AO2
  route_attn_kernel<<<(H_NUM * N_TOK) / 4, 256, 0, stream>>>(qbuf, cent, kbf,
                                                             vbf, AO2);
  // 5. proj GEMM (MFMA swizzled, 3 products) + bias
  {
    dim3 grid(C_DIM / 64, N_TOK / 64);
    gemm_mfma<<<grid, 256, 0, stream>>>(AO2, WP2, nullptr, out, b_proj, C_DIM, 1);
  }
}

// Round 16
// 175.080 us; speedup vs baseline: 1.0394x; 1.0394x over previous
//
#include <hip/hip_runtime.h>
#include <hip/hip_bf16.h>
#include <math.h>

#define N_TOK 2048
#define C_DIM 512
#define H_NUM 8
#define DH 64
#define M_LM 64
#define SEG 32
#define KL 4
#define SCALE 0.125f

typedef __attribute__((ext_vector_type(8))) short short8;
typedef __attribute__((ext_vector_type(8))) unsigned short ushort8v;
typedef __attribute__((ext_vector_type(4))) float f32x4;

__device__ inline unsigned short f2bf(float f) {
  unsigned u = __float_as_uint(f);
  u += 0x7FFF + ((u >> 16) & 1);
  return (unsigned short)(u >> 16);
}
__device__ inline float bf2f(unsigned short h) {
  return __uint_as_float(((unsigned)h) << 16);
}

// LDS swizzle for the MFMA GEMM (R7-proven): k-octet stride 1024B is 0 mod 32
// banks; XOR row bits with ko, same on write and read => layout-only.
__device__ inline int swz(int ko, int row) {
  return ((ko * 64 + row) * 8) ^ (ko << 3);
}

// gemm_qk staging rotation (R10-proven: conflicts 3.15M -> 0).
__device__ inline int qrot(int k, int c) {
  return (c & ~3) | ((c + (k >> 3)) & 3);
}

// ---------------------------------------------------------------------------
// FUSED: Q/K fp32 GEMM (R13 body, blocks [0,512), byte-identical tiles via
// b&15 / b>>4) + elementwise 2-term bf16 splits (blocks [512,896), 16
// elems/thread, float4 loads). Split is elementwise (per-element f2bf chain,
// no reductions) => thread remapping is value-exact; X2/W2v/WP2 bit-identical
// to the old split3_kernel. Split blocks tail-fill CUs as qk blocks retire
// (qk = long pole at 2 blocks/CU), hiding split3's ~8us body + one launch
// gap. R3's fusion failure (two loop-heavy bodies, VGPR union 136, 18M
// conflicts) does not apply: this grafts a trivial straight-line body.
// qk itself CLOSED at ~92% of its LDS-pipe floor (R5/R6/R8/R9/R11/R12).
// ---------------------------------------------------------------------------
__global__ __launch_bounds__(256) void gemm_qk(
    const float* __restrict__ A, const float* __restrict__ B,
    float* __restrict__ out_q, unsigned short* __restrict__ kbf,
    float* __restrict__ cent,
    const float* __restrict__ wv, const float* __restrict__ wp,
    unsigned short* __restrict__ X2, unsigned short* __restrict__ W2v,
    unsigned short* __restrict__ WP2)
{
  __shared__ float As[32][68];   // [k][m], pad->16B-aligned rows
  __shared__ float Bs[32][68];   // [k][j]
  int tid = threadIdx.x;
  int b = blockIdx.x;

  if (b >= 512) {
    // ---- split role: 16 consecutive elements per thread (value-exact) ----
    int c = (b - 512) * 256 + tid;   // 0..98303
    const float* src; unsigned short* dst; int li;
    if (c < 65536)      { src = A;  dst = X2;  li = c << 4; }
    else if (c < 81920) { src = wv; dst = W2v; li = (c - 65536) << 4; }
    else                { src = wp; dst = WP2; li = (c - 81920) << 4; }
    int r = li >> 9, k = li & 511;   // 512%16==0 -> all 16 elems in one row
    ushort8v hi8[2], lo8[2];
#pragma unroll
    for (int v = 0; v < 4; v++) {
      float4 f = *(const float4*)(src + li + v * 4);
      float e[4] = {f.x, f.y, f.z, f.w};
#pragma unroll
      for (int j = 0; j < 4; j++) {
        unsigned short h1 = f2bf(e[j]);
        float r1 = e[j] - bf2f(h1);
        hi8[v >> 1][(v & 1) * 4 + j] = (short)h1;
        lo8[v >> 1][(v & 1) * 4 + j] = (short)f2bf(r1);
      }
    }
    size_t base = (size_t)(r << 10) + k;
    *(ushort8v*)(dst + base)       = hi8[0];
    *(ushort8v*)(dst + base + 8)   = hi8[1];
    *(ushort8v*)(dst + base + 512) = lo8[0];
    *(ushort8v*)(dst + base + 520) = lo8[1];
    return;
  }

  // ---- qk role (R13 body, byte-identical) ----
  int tx = tid & 15, ty = tid >> 4;
  int row0 = (b >> 4) << 6;
  int col0 = (b & 15) << 6;
  float acc[4][4] = {};
  int kk = tid & 31, rr = tid >> 5;   // staging: 32 k-cols x 8 row-groups

  float pa[8], pb[8];
#pragma unroll
  for (int i = 0; i < 8; i++) {
    pa[i] = A[(size_t)(row0 + rr + i * 8) * 512 + kk];
    pb[i] = B[(size_t)(col0 + rr + i * 8) * 512 + kk];
  }

  for (int k0 = 0; k0 < 512; k0 += 32) {
    __syncthreads();
#pragma unroll
    for (int i = 0; i < 8; i++) {
      As[kk][qrot(kk, rr + i * 8)] = pa[i];
      Bs[kk][qrot(kk, rr + i * 8)] = pb[i];
    }
    __syncthreads();
    if (k0 + 32 < 512) {
#pragma unroll
      for (int i = 0; i < 8; i++) {
        pa[i] = A[(size_t)(row0 + rr + i * 8) * 512 + k0 + 32 + kk];
        pb[i] = B[(size_t)(col0 + rr + i * 8) * 512 + k0 + 32 + kk];
      }
    }
#pragma unroll
    for (int kk2 = 0; kk2 < 32; kk2++) {
      const int a2 = kk2 >> 3;
      float ar[4], br[4];
      *(float4*)ar = *(const float4*)&As[kk2][ty << 2];
      *(float4*)br = *(const float4*)&Bs[kk2][tx << 2];
      float a[4], bb[4];
#pragma unroll
      for (int j = 0; j < 4; j++) {
        a[j]  = ar[(j + a2) & 3];
        bb[j] = br[(j + a2) & 3];
      }
#pragma unroll
      for (int i = 0; i < 4; i++)
#pragma unroll
        for (int j = 0; j < 4; j++) acc[i][j] += a[i] * bb[j];
    }
  }

  int role = col0 >> 9;
  int h = (col0 >> 6) & 7;
  if (role == 0) {
#pragma unroll
    for (int i = 0; i < 4; i++) {
      int n = row0 + (ty << 2) + i;
#pragma unroll
      for (int j = 0; j < 4; j++) {
        int d = (tx << 2) + j;
        out_q[(size_t)((h << 11) + n) * DH + d] = acc[i][j];
      }
    }
  } else {
    // bf16 K store + exact-order fused centroid (reuses dead As/Bs).
    __syncthreads();   // all lanes done reading As/Bs from the main loop
#pragma unroll
    for (int i = 0; i < 4; i++) {
      int nl = (ty << 2) + i;          // local row 0..63
#pragma unroll
      for (int j = 0; j < 4; j++) {
        int d = (tx << 2) + j;
        float v = acc[i][j];
        kbf[(size_t)((h << 11) + row0 + nl) * DH + d] = f2bf(v);
        if (nl < 32) As[nl][d] = v; else Bs[nl - 32][d] = v;
      }
    }
    __syncthreads();
    if (tid < 128) {
      int m_loc = tid >> 6, d = tid & 63;
      float s = 0.f;
      if (m_loc == 0) {
#pragma unroll
        for (int ss = 0; ss < SEG; ss++) s += As[ss][d];   // ascending n
      } else {
#pragma unroll
        for (int ss = 0; ss < SEG; ss++) s += Bs[ss][d];   // ascending n
      }
      int m = (row0 >> 5) + m_loc;
      cent[(h << 12) + (m << 6) + d] = s * (1.0f / SEG);
    }
  }
}

// ---------------------------------------------------------------------------
// bf16-split MFMA GEMM, 3 products + LDS XOR swizzle (R7-proven).
// mode 0: V-scatter as SINGLE bf16 -> ov16[(h<<11)+row][d]
// mode 1: ofull = acc + bias (fp32).
// ---------------------------------------------------------------------------
__global__ __launch_bounds__(256) void gemm_mfma(
    const unsigned short* __restrict__ A2, const unsigned short* __restrict__ B2,
    unsigned short* __restrict__ ov16, float* __restrict__ ofull,
    const float* __restrict__ bias, int ldout, int mode)
{
  __shared__ short Al[4096];
  __shared__ short Bl[4096];
  int tid = threadIdx.x;
  int lane = tid & 63, w = tid >> 6;
  int row0 = blockIdx.y << 6, col0 = blockIdx.x << 6;
  int wr = (w >> 1) * 32, wc = (w & 1) * 32;
  int m_lo = tid & 7, h8 = (tid >> 3) & 7, m_hi = tid >> 6;
  int ms = m_hi * 8 + m_lo;  // 0..31
  int q = lane >> 4, ln = lane & 15;

  f32x4 acc[2][2];
#pragma unroll
  for (int mi = 0; mi < 2; mi++)
#pragma unroll
    for (int ni = 0; ni < 2; ni++)
#pragma unroll
      for (int r = 0; r < 4; r++) acc[mi][ni][r] = 0.0f;

  for (int s = 0; s < 24; s++) {
    int ka = (s < 8) ? s * 64 : (s < 16) ? 512 + (s - 8) * 64 : (s - 16) * 64;
    int kb = (s < 8) ? s * 64 : (s < 16) ? (s - 8) * 64 : 512 + (s - 16) * 64;
    short8 a0 = *(const short8*)(A2 + (size_t)(row0 + ms) * 1024 + ka + h8 * 8);
    short8 a1 = *(const short8*)(A2 + (size_t)(row0 + ms + 32) * 1024 + ka + h8 * 8);
    short8 b0 = *(const short8*)(B2 + (size_t)(col0 + ms) * 1024 + kb + h8 * 8);
    short8 b1 = *(const short8*)(B2 + (size_t)(col0 + ms + 32) * 1024 + kb + h8 * 8);
    __syncthreads();
    *(short8*)&Al[swz(h8, ms)] = a0;
    *(short8*)&Al[swz(h8, ms + 32)] = a1;
    *(short8*)&Bl[swz(h8, ms)] = b0;
    *(short8*)&Bl[swz(h8, ms + 32)] = b1;
    __syncthreads();
    short8 af[2][2], bf[2][2];
#pragma unroll
    for (int sub = 0; sub < 2; sub++)
#pragma unroll
      for (int i = 0; i < 2; i++) {
        af[sub][i] = *(const short8*)&Al[swz(sub * 4 + q, wr + i * 16 + ln)];
        bf[sub][i] = *(const short8*)&Bl[swz(sub * 4 + q, wc + i * 16 + ln)];
      }
#pragma unroll
    for (int sub = 0; sub < 2; sub++)
#pragma unroll
      for (int mi = 0; mi < 2; mi++)
#pragma unroll
        for (int ni = 0; ni < 2; ni++)
          acc[mi][ni] = __builtin_amdgcn_mfma_f32_16x16x32_bf16(
              af[sub][mi], bf[sub][ni], acc[mi][ni], 0, 0, 0);
  }

  if (mode == 0) {
    int hh = (col0 >> 6) & 7;
#pragma unroll
    for (int mi = 0; mi < 2; mi++)
#pragma unroll
      for (int ni = 0; ni < 2; ni++)
#pragma unroll
        for (int r = 0; r < 4; r++) {
          int row = row0 + wr + mi * 16 + q * 4 + r;
          int d = wc + ni * 16 + ln;
          ov16[(size_t)((hh << 11) + row) * DH + d] = f2bf(acc[mi][ni][r]);
        }
  } else {
#pragma unroll
    for (int mi = 0; mi < 2; mi++)
#pragma unroll
      for (int ni = 0; ni < 2; ni++)
#pragma unroll
        for (int r = 0; r < 4; r++) {
          int row = row0 + wr + mi * 16 + q * 4 + r;
          int col = col0 + wc + ni * 16 + ln;
          ofull[(size_t)row * ldout + col] = acc[mi][ni][r] + bias[col];
        }
  }
}

// ---------------------------------------------------------------------------
// FUSED route + top-4 + sparse attention (R14 body; R15's head-pin swizzle
// REVERTED — null/slightly negative, gather is latency-bound not capacity-
// bound; L3 already absorbs cross-XCD duplication).
// ---------------------------------------------------------------------------
__global__ __launch_bounds__(256) void route_attn_kernel(
    const float* __restrict__ qb, const float* __restrict__ cent,
    const unsigned short* __restrict__ kbf, const unsigned short* __restrict__ vbf,
    unsigned short* __restrict__ ao2)
{
  __shared__ float centT[64][65];
  __shared__ float qs[4][64];
  __shared__ float probs[4][132];   // [wave][si*33 + ss]
  int tid = threadIdx.x;
  int wave = tid >> 6, lane = tid & 63;
  int qi = (blockIdx.x << 2) + wave;
  int h = qi >> 11, n = qi & 2047;   // h uniform across block (2048 % 4 == 0)

  // ---- route phase (frozen math) ----
  qs[wave][lane] = qb[(size_t)qi * DH + lane];
  const float4* c4 = (const float4*)(cent + ((size_t)h << 12));
#pragma unroll
  for (int i = 0; i < 4; i++) {
    int f4 = tid + 256 * i;       // 0..1023
    int m = f4 >> 4;
    int d0 = (f4 & 15) * 4;
    float4 v = c4[f4];
    centT[d0][m] = v.x; centT[d0 + 1][m] = v.y;
    centT[d0 + 2][m] = v.z; centT[d0 + 3][m] = v.w;
  }
  __syncthreads();
  float dot = 0.f;
#pragma unroll
  for (int d = 0; d < 64; d++) dot += qs[wave][d] * centT[d][lane];
  float val = dot * SCALE;
  int segArr[4];
  for (int r = 0; r < KL; r++) {
    float v = val;
    int id = lane;
#pragma unroll
    for (int off = 32; off; off >>= 1) {
      float ov = __shfl_xor(v, off, 64);
      int oi = __shfl_xor(id, off, 64);
      if (ov > v || (ov == v && oi < id)) { v = ov; id = oi; }
    }
    segArr[r] = id;                  // all lanes converged to the same id
    if (lane == id) val = -INFINITY;
  }

  // ---- attn phase (frozen math; q fragments from qs, same bits) ----
  const float* qrow = &qs[wave][0];
  float4 qreg[4];
#pragma unroll
  for (int j = 0; j < 2; j++) {
    qreg[j * 2]     = *(const float4*)(qrow + ((lane & 3) + 4 * j) * 8);
    qreg[j * 2 + 1] = *(const float4*)(qrow + ((lane & 3) + 4 * j) * 8 + 4);
  }

  float e[8];
  float score[8];
#pragma unroll
  for (int g = 0; g < 8; g++) {
    int seg = segArr[g >> 1];
    int key_n = seg * SEG + (lane >> 2) + 16 * (g & 1);
    const unsigned short* krow = kbf + ((size_t)(h << 11) + key_n) * DH;
    float a0 = 0.f, a1 = 0.f, a2 = 0.f, a3 = 0.f;
#pragma unroll
    for (int j = 0; j < 2; j++) {
      ushort8v kv = *(const ushort8v*)(krow + ((lane & 3) + 4 * j) * 8);
      float4 q0 = qreg[j * 2], q1 = qreg[j * 2 + 1];
      a0 += q0.x * bf2f(kv[0]); a1 += q0.y * bf2f(kv[1]);
      a2 += q0.z * bf2f(kv[2]); a3 += q0.w * bf2f(kv[3]);
      a0 += q1.x * bf2f(kv[4]); a1 += q1.y * bf2f(kv[5]);
      a2 += q1.z * bf2f(kv[6]); a3 += q1.w * bf2f(kv[7]);
    }
    float acc = (a0 + a1) + (a2 + a3);
    acc += __shfl_xor(acc, 1, 64);
    acc += __shfl_xor(acc, 2, 64);
    score[g] = acc * SCALE;
  }
  float mx = score[0];
#pragma unroll
  for (int g = 1; g < 8; g++) mx = fmaxf(mx, score[g]);
#pragma unroll
  for (int off = 4; off < 64; off <<= 1) mx = fmaxf(mx, __shfl_xor(mx, off, 64));
  float ls = 0.f;
#pragma unroll
  for (int g = 0; g < 8; g++) { e[g] = expf(score[g] - mx); ls += e[g]; }
#pragma unroll
  for (int off = 4; off < 64; off <<= 1) ls += __shfl_xor(ls, off, 64);
  float inv = 1.0f / ls;
  if ((lane & 3) == 0) {
#pragma unroll
    for (int g = 0; g < 8; g++)
      probs[wave][(g >> 1) * 33 + (lane >> 2) + 16 * (g & 1)] = e[g] * inv;
  }
  __syncthreads();

  // PV
  int gi = lane >> 4, lx = lane & 15;
  int rh = lx >> 3, dl = lx & 7;
  int seg = segArr[gi];
  const unsigned short* vbase = vbf + ((size_t)(h << 11) + seg * SEG) * DH + dl * 8;
  float o[8] = {};
#pragma unroll
  for (int ss = 0; ss < 16; ss++) {
    int row = rh * 16 + ss;
    float p = probs[wave][gi * 33 + row];
    ushort8v vv = *(const ushort8v*)(vbase + (size_t)row * DH);
#pragma unroll
    for (int j = 0; j < 8; j++) o[j] += p * bf2f(vv[j]);
  }
#pragma unroll
  for (int off = 8; off < 64; off <<= 1) {
#pragma unroll
    for (int j = 0; j < 8; j++) o[j] += __shfl_xor(o[j], off, 64);
  }
  if (lane < 8) {
    ushort8v hi8, lo8;
#pragma unroll
    for (int j = 0; j < 8; j++) {
      unsigned short hb = f2bf(o[j]);
      hi8[j] = (short)hb;
      lo8[j] = (short)f2bf(o[j] - bf2f(hb));
    }
    *(ushort8v*)(ao2 + (size_t)n * 1024 + (h << 6) + (lane << 3)) = hi8;
    *(ushort8v*)(ao2 + (size_t)n * 1024 + 512 + (h << 6) + (lane << 3)) = lo8;
  }
}

// ---------------------------------------------------------------------------
extern "C" void kernel_launch(void* const* d_in, const int* in_sizes, int n_in,
                              void* d_out, int out_size, void* d_ws, size_t ws_size,
                              hipStream_t stream)
{
  const float* x      = (const float*)d_in[0];   // (1,2048,512)
  const float* w_qkv  = (const float*)d_in[1];   // (1536,512)
  const float* w_proj = (const float*)d_in[2];   // (512,512)
  const float* b_proj = (const float*)d_in[3];   // (512,)
  float* out = (float*)d_out;                    // (1,2048,512)

  float* base = (float*)d_ws;
  float* qbuf = base;                                        // 1,048,576 f
  // base+1048576 slot free (fp32 K dead since R13)
  unsigned short* vbf = (unsigned short*)(base + 2097152);   // 8x2048x64 bf16
  unsigned short* kbf = (unsigned short*)(base + 2621440);   // 8x2048x64 bf16
  float* cent = base + 3145728;                              // 32,768 f
  unsigned short* X2  = (unsigned short*)(base + 3244032);   // 2048x1024 bf16 (2-term)
  unsigned short* W2v = (unsigned short*)(base + 4292608);   // 512x1024  (V rows of w_qkv)
  unsigned short* WP2 = (unsigned short*)(base + 4554752);   // 512x1024  (w_proj)
  unsigned short* AO2 = X2;  // overlay: X2 dead after V GEMM

  // 1. FUSED: Q/K fp32 GEMM (blocks 0-511, R13 body) + bf16 K + exact
  //    centroid + elementwise splits (blocks 512-895) -> X2/W2v/WP2
  gemm_qk<<<896, 256, 0, stream>>>(x, w_qkv, qbuf, kbf, cent,
                                   w_qkv + 1024 * 512, w_proj, X2, W2v, WP2);
  // 2. V via bf16-split MFMA (swizzled LDS) -> single-bf16 vbf
  {
    dim3 grid(512 / 64, N_TOK / 64);
    gemm_mfma<<<grid, 256, 0, stream>>>(X2, W2v, vbf, nullptr, nullptr, 0, 0);
  }
  // 3. fused route + top-4 + attn (R14 mapping) -> 2-term AO2 (overlays X2)
  route_attn_kernel<<<(H_NUM * N_TOK) / 4, 256, 0, stream>>>(qbuf, cent, kbf,
                                                             vbf, AO2);
  // 4. proj GEMM (MFMA swizzled, 3 products) + bias
  {
    dim3 grid(C_DIM / 64, N_TOK / 64);
    gemm_mfma<<<grid, 256, 0, stream>>>(AO2, WP2, nullptr, out, b_proj, C_DIM, 1);
  }
}